// Round 2
// baseline (23636.778 us; speedup 1.0000x reference)
//
#include <hip/hip_runtime.h>
#include <hip/hip_bf16.h>

// Neural ODE Euler rollout, persistent weight-stationary model-parallel kernel.
// B=256, T=128, X=256, H=1024, L=3.
// 4 groups x 64 blocks; group g owns batch rows [64g,64g+64).
// Block j in group owns N-slice cols [16j,16j+16) of H (and of X for j<16),
// with W_in/W_h[0..2]/W_out slices resident in LDS (fragment-major, ~137KB).
// 5 phases per step, group barrier between phases (monotonic atomic counter).

typedef __attribute__((ext_vector_type(8))) short short8;
typedef __attribute__((ext_vector_type(4))) float f32x4;

__device__ inline unsigned short f2bf(float f) {
  unsigned u = __builtin_bit_cast(unsigned, f);
  unsigned r = u + 0x7FFFu + ((u >> 16) & 1u);
  return (unsigned short)(r >> 16);
}

__global__ __launch_bounds__(256, 1) void node_persistent(
    const float* __restrict__ x, const float* __restrict__ ts,
    const float* __restrict__ Win, const float* __restrict__ bin,
    const float* __restrict__ Wh, const float* __restrict__ bh,
    const float* __restrict__ Wout, const float* __restrict__ bout,
    float* __restrict__ out,
    unsigned* __restrict__ cnt,
    unsigned short* __restrict__ ybf,
    unsigned short* __restrict__ a0,
    unsigned short* __restrict__ a1) {
  // LDS: fragment-major weight slices. Element (k,c) -> ((k>>3)*16 + c)*8 + (k&7)
  alignas(16) __shared__ unsigned short sWin[256 * 16];        // 8 KB
  alignas(16) __shared__ unsigned short sWh[3][1024 * 16];     // 96 KB
  alignas(16) __shared__ unsigned short sWout[1024 * 16];      // 32 KB
  __shared__ float sBin[16], sBh[3][16], sBout[16];

  const int bid = blockIdx.x;
  // XCD-locality swizzle: group g lives on XCD pair {2g,2g+1} (heuristic only).
  const int g = (bid & 7) >> 1;                 // group 0..3
  const int j = ((bid >> 3) << 1) | (bid & 1);  // n-slice 0..63
  const int tid = threadIdx.x;
  const int w = tid >> 6;       // wave 0..3 -> 16-row M tile
  const int l = tid & 63;       // lane
  const int lr = l & 15;        // A row / B col / D col
  const int lk = l >> 4;        // k-chunk; D rows = 4*lk + r
  const int rowbase = g * 64 + w * 16;
  unsigned* gcnt = cnt + g * 64;  // 256B apart per group

  // ---- stage resident weights into LDS (once per launch) ----
  for (int idx = tid; idx < 256 * 16; idx += 256) {
    int k = idx >> 4, c = idx & 15;
    sWin[((k >> 3) * 16 + c) * 8 + (k & 7)] = f2bf(Win[k * 1024 + j * 16 + c]);
  }
  for (int l3 = 0; l3 < 3; ++l3)
    for (int idx = tid; idx < 1024 * 16; idx += 256) {
      int k = idx >> 4, c = idx & 15;
      sWh[l3][((k >> 3) * 16 + c) * 8 + (k & 7)] =
          f2bf(Wh[(l3 * 1024 + k) * 1024 + j * 16 + c]);
    }
  if (j < 16) {
    for (int idx = tid; idx < 1024 * 16; idx += 256) {
      int k = idx >> 4, c = idx & 15;
      sWout[((k >> 3) * 16 + c) * 8 + (k & 7)] = f2bf(Wout[k * 256 + j * 16 + c]);
    }
  }
  if (tid < 16) {
    sBin[tid] = bin[j * 16 + tid];
    sBh[0][tid] = bh[j * 16 + tid];
    sBh[1][tid] = bh[1024 + j * 16 + tid];
    sBh[2][tid] = bh[2048 + j * 16 + tid];
    if (j < 16) sBout[tid] = bout[j * 16 + tid];
  }

  // ---- init y (fp32 in registers of owner blocks), ybf, out[:,0,:] ----
  f32x4 yreg = {0.f, 0.f, 0.f, 0.f};
  if (j < 16) {
    for (int idx = tid; idx < 64 * 16; idx += 256) {
      int r = idx >> 4, c = idx & 15;
      int row = g * 64 + r, col = j * 16 + c;
      float v = x[row * 256 + col];
      ybf[row * 256 + col] = f2bf(v);
      out[(row * 128) * 256 + col] = v;  // pred[:,0,:] = x (exact fp32)
    }
#pragma unroll
    for (int r4 = 0; r4 < 4; ++r4)
      yreg[r4] = x[(rowbase + lk * 4 + r4) * 256 + j * 16 + lr];
  }

  unsigned bn = 0;
  auto BAR = [&]() {
    ++bn;
    __threadfence();      // release: drain this thread's stores to coherence pt
    __syncthreads();
    if (tid == 0) {
      __hip_atomic_fetch_add(gcnt, 1u, __ATOMIC_RELEASE, __HIP_MEMORY_SCOPE_AGENT);
      while (__hip_atomic_load(gcnt, __ATOMIC_RELAXED, __HIP_MEMORY_SCOPE_AGENT) <
             64u * bn)
        __builtin_amdgcn_s_sleep(1);
      __threadfence();    // acquire: invalidate CU/L2 caches before reads
    }
    __syncthreads();
  };

  BAR();  // weights + init visible group-wide

  const int colH = j * 16 + lr;
  for (int t = 0; t < 127; ++t) {
    // ---- Phase A: h1 = y @ W_in + b_in ; a0 = tanh(h1) ----
    {
      f32x4 acc = {0.f, 0.f, 0.f, 0.f};
      const unsigned short* arow = ybf + (rowbase + lr) * 256 + lk * 8;
      const unsigned short* bbase = sWin + lk * 128 + lr * 8;
#pragma unroll
      for (int kk = 0; kk < 8; ++kk) {
        short8 a = *(const short8*)(arow + kk * 32);
        short8 b = *(const short8*)(bbase + kk * 512);
        acc = __builtin_amdgcn_mfma_f32_16x16x32_bf16(a, b, acc, 0, 0, 0);
      }
      float bias = sBin[lr];
#pragma unroll
      for (int r4 = 0; r4 < 4; ++r4) {
        float v = tanhf(acc[r4] + bias);
        a0[(rowbase + lk * 4 + r4) * 1024 + colH] = f2bf(v);
      }
    }
    BAR();
    // ---- Phases B,C,D: h = tanh(h_prev) @ W_h[l3] + b_h[l3]; tanh on write ----
    for (int l3 = 0; l3 < 3; ++l3) {
      const unsigned short* src = (l3 & 1) ? a1 : a0;
      unsigned short* dst = (l3 & 1) ? a0 : a1;
      f32x4 acc = {0.f, 0.f, 0.f, 0.f};
      const unsigned short* arow = src + (rowbase + lr) * 1024 + lk * 8;
      const unsigned short* bbase = sWh[l3] + lk * 128 + lr * 8;
#pragma unroll 8
      for (int kk = 0; kk < 32; ++kk) {
        short8 a = *(const short8*)(arow + kk * 32);
        short8 b = *(const short8*)(bbase + kk * 512);
        acc = __builtin_amdgcn_mfma_f32_16x16x32_bf16(a, b, acc, 0, 0, 0);
      }
      float bias = sBh[l3][lr];
#pragma unroll
      for (int r4 = 0; r4 < 4; ++r4) {
        float v = tanhf(acc[r4] + bias);
        dst[(rowbase + lk * 4 + r4) * 1024 + colH] = f2bf(v);
      }
      BAR();
    }
    // ---- Phase E: f = a1 @ W_out + b_out ; y += dt*f ; emit out[:,t+1,:] ----
    float dt = ts[t + 1] - ts[t];
    if (j < 16) {
      f32x4 acc = {0.f, 0.f, 0.f, 0.f};
      const unsigned short* arow = a1 + (rowbase + lr) * 1024 + lk * 8;
      const unsigned short* bbase = sWout + lk * 128 + lr * 8;
#pragma unroll 8
      for (int kk = 0; kk < 32; ++kk) {
        short8 a = *(const short8*)(arow + kk * 32);
        short8 b = *(const short8*)(bbase + kk * 512);
        acc = __builtin_amdgcn_mfma_f32_16x16x32_bf16(a, b, acc, 0, 0, 0);
      }
      int col = j * 16 + lr;
#pragma unroll
      for (int r4 = 0; r4 < 4; ++r4) {
        float f = acc[r4] + sBout[lr];
        float yv = yreg[r4] + dt * f;
        yreg[r4] = yv;
        int row = rowbase + lk * 4 + r4;
        ybf[row * 256 + col] = f2bf(yv);
        out[(row * 128 + t + 1) * 256 + col] = yv;
      }
    }
    BAR();
  }
}

extern "C" void kernel_launch(void* const* d_in, const int* in_sizes, int n_in,
                              void* d_out, int out_size, void* d_ws, size_t ws_size,
                              hipStream_t stream) {
  (void)in_sizes; (void)n_in; (void)out_size; (void)ws_size;
  const float* x    = (const float*)d_in[0];
  const float* ts   = (const float*)d_in[1];
  const float* Win  = (const float*)d_in[2];
  const float* bin  = (const float*)d_in[3];
  const float* Wh   = (const float*)d_in[4];
  const float* bh   = (const float*)d_in[5];
  const float* Wout = (const float*)d_in[6];
  const float* bout = (const float*)d_in[7];
  float* out = (float*)d_out;

  char* ws = (char*)d_ws;
  unsigned* cnt = (unsigned*)ws;                                   // 4 KB counters
  unsigned short* ybf = (unsigned short*)(ws + 4096);              // 128 KB bf16 y
  unsigned short* a0 = (unsigned short*)(ws + 4096 + 131072);      // 512 KB
  unsigned short* a1 = (unsigned short*)(ws + 4096 + 131072 + 524288);  // 512 KB

  hipMemsetAsync(ws, 0, 4096, stream);  // zero barrier counters each call

  // Persistent spin-barrier kernel: co-residency of all 256 blocks is required.
  // Cooperative launch guarantees it; fall back to plain launch if rejected.
  void* args[] = {(void*)&x,    (void*)&ts,  (void*)&Win,  (void*)&bin,
                  (void*)&Wh,   (void*)&bh,  (void*)&Wout, (void*)&bout,
                  (void*)&out,  (void*)&cnt, (void*)&ybf,  (void*)&a0,
                  (void*)&a1};
  hipError_t e = hipLaunchCooperativeKernel((const void*)node_persistent,
                                            dim3(256), dim3(256), args, 0, stream);
  if (e != hipSuccess) {
    hipLaunchKernelGGL(node_persistent, dim3(256), dim3(256), 0, stream,
                       x, ts, Win, bin, Wh, bh, Wout, bout, out, cnt, ybf, a0, a1);
  }
}

// Round 3
// 5086.476 us; speedup vs baseline: 4.6470x; 4.6470x over previous
//
#include <hip/hip_runtime.h>
#include <hip/hip_bf16.h>

// Neural ODE Euler rollout, persistent weight-stationary model-parallel kernel.
// B=256, T=128, X=256, H=1024, L=3.
// 4 groups x 64 blocks; group g owns batch rows [64g,64g+64).
// Block j in group owns N-slice cols [16j,16j+16) of H (and of X for j<16),
// with W_in/W_h[0..2]/W_out slices resident in LDS (fragment-major, ~137KB).
// 5 phases per step, group barrier between phases (monotonic atomic counter).
//
// Round-3 change: NO __threadfence in the loop (gfx950 agent fences emit
// buffer_wbl2/buffer_inv = full-L2 maintenance, ~37us/phase in Round 2).
// All cross-block activation traffic uses relaxed agent-scope atomics
// (global_load/store ... sc0 sc1: L1/L2-bypassing, coherent at IF$), so the
// barrier needs only vmcnt-drain (inside __syncthreads) + relaxed counter.

typedef __attribute__((ext_vector_type(8))) short short8;
typedef __attribute__((ext_vector_type(4))) float f32x4;

#define AT_LD(p) __hip_atomic_load((p), __ATOMIC_RELAXED, __HIP_MEMORY_SCOPE_AGENT)
#define AT_ST(p, v) \
  __hip_atomic_store((p), (v), __ATOMIC_RELAXED, __HIP_MEMORY_SCOPE_AGENT)

__device__ inline unsigned short f2bf(float f) {
  unsigned u = __builtin_bit_cast(unsigned, f);
  unsigned r = u + 0x7FFFu + ((u >> 16) & 1u);
  return (unsigned short)(r >> 16);
}

// 16B coherent fragment load as 2x8B relaxed agent atomics (sc0 sc1).
__device__ inline short8 ld_frag(const unsigned short* p) {
  union {
    unsigned long long q[2];
    short8 v;
  } u;
  unsigned long long* q = (unsigned long long*)p;
  u.q[0] = AT_LD(q);
  u.q[1] = AT_LD(q + 1);
  return u.v;
}

__global__ __launch_bounds__(256, 1) void node_persistent(
    const float* __restrict__ x, const float* __restrict__ ts,
    const float* __restrict__ Win, const float* __restrict__ bin,
    const float* __restrict__ Wh, const float* __restrict__ bh,
    const float* __restrict__ Wout, const float* __restrict__ bout,
    float* __restrict__ out,
    unsigned* __restrict__ cnt,
    unsigned short* __restrict__ ybf,
    unsigned short* __restrict__ a0,
    unsigned short* __restrict__ a1) {
  // LDS: fragment-major weight slices. Element (k,c) -> ((k>>3)*16 + c)*8 + (k&7)
  alignas(16) __shared__ unsigned short sWin[256 * 16];        // 8 KB
  alignas(16) __shared__ unsigned short sWh[3][1024 * 16];     // 96 KB
  alignas(16) __shared__ unsigned short sWout[1024 * 16];      // 32 KB
  __shared__ float sBin[16], sBh[3][16], sBout[16];
  __shared__ float sDt[128];

  const int bid = blockIdx.x;
  // XCD-locality swizzle: group g lives on XCD pair {2g,2g+1} (heuristic only).
  const int g = (bid & 7) >> 1;                 // group 0..3
  const int j = ((bid >> 3) << 1) | (bid & 1);  // n-slice 0..63
  const int tid = threadIdx.x;
  const int w = tid >> 6;       // wave 0..3 -> 16-row M tile
  const int l = tid & 63;       // lane
  const int lr = l & 15;        // A row / B col / D col
  const int lk = l >> 4;        // k-chunk; D rows = 4*lk + r
  const int rowbase = g * 64 + w * 16;
  unsigned* gcnt = cnt + g * 64;  // 256B apart per group

  // ---- stage resident weights into LDS (once per launch) ----
  for (int idx = tid; idx < 256 * 16; idx += 256) {
    int k = idx >> 4, c = idx & 15;
    sWin[((k >> 3) * 16 + c) * 8 + (k & 7)] = f2bf(Win[k * 1024 + j * 16 + c]);
  }
  for (int l3 = 0; l3 < 3; ++l3)
    for (int idx = tid; idx < 1024 * 16; idx += 256) {
      int k = idx >> 4, c = idx & 15;
      sWh[l3][((k >> 3) * 16 + c) * 8 + (k & 7)] =
          f2bf(Wh[(l3 * 1024 + k) * 1024 + j * 16 + c]);
    }
  if (j < 16) {
    for (int idx = tid; idx < 1024 * 16; idx += 256) {
      int k = idx >> 4, c = idx & 15;
      sWout[((k >> 3) * 16 + c) * 8 + (k & 7)] = f2bf(Wout[k * 256 + j * 16 + c]);
    }
  }
  if (tid < 16) {
    sBin[tid] = bin[j * 16 + tid];
    sBh[0][tid] = bh[j * 16 + tid];
    sBh[1][tid] = bh[1024 + j * 16 + tid];
    sBh[2][tid] = bh[2048 + j * 16 + tid];
    if (j < 16) sBout[tid] = bout[j * 16 + tid];
  }
  if (tid < 127) sDt[tid] = ts[tid + 1] - ts[tid];

  // ---- init y (fp32 in registers of owner blocks), ybf, out[:,0,:] ----
  f32x4 yreg = {0.f, 0.f, 0.f, 0.f};
  if (j < 16) {
    for (int idx = tid; idx < 64 * 16; idx += 256) {
      int r = idx >> 4, c = idx & 15;
      int row = g * 64 + r, col = j * 16 + c;
      float v = x[row * 256 + col];
      AT_ST(&ybf[row * 256 + col], f2bf(v));   // coherent: consumers bypass L2
      out[(row * 128) * 256 + col] = v;        // pred[:,0,:] = x (host-read only)
    }
#pragma unroll
    for (int r4 = 0; r4 < 4; ++r4)
      yreg[r4] = x[(rowbase + lk * 4 + r4) * 256 + j * 16 + lr];
  }

  unsigned bn = 0;
  auto BAR = [&]() {
    ++bn;
    // __syncthreads() lowers to s_waitcnt vmcnt(0) lgkmcnt(0) + s_barrier:
    // all this block's coherent (sc0 sc1) stores are at the IF$ before arrival.
    __syncthreads();
    if (tid == 0) {
      __hip_atomic_fetch_add(gcnt, 1u, __ATOMIC_RELAXED, __HIP_MEMORY_SCOPE_AGENT);
      while (AT_LD(gcnt) < 64u * bn) __builtin_amdgcn_s_sleep(1);
    }
    __syncthreads();
  };

  BAR();  // weights + init visible group-wide

  const int colH = j * 16 + lr;
  for (int t = 0; t < 127; ++t) {
    // ---- Phase A: h1 = y @ W_in + b_in ; a0 = tanh(h1) ----
    {
      f32x4 acc = {0.f, 0.f, 0.f, 0.f};
      const unsigned short* arow = ybf + (rowbase + lr) * 256 + lk * 8;
      const unsigned short* bbase = sWin + lk * 128 + lr * 8;
#pragma unroll
      for (int kk = 0; kk < 8; ++kk) {
        short8 a = ld_frag(arow + kk * 32);
        short8 b = *(const short8*)(bbase + kk * 512);
        acc = __builtin_amdgcn_mfma_f32_16x16x32_bf16(a, b, acc, 0, 0, 0);
      }
      float bias = sBin[lr];
#pragma unroll
      for (int r4 = 0; r4 < 4; ++r4) {
        float v = tanhf(acc[r4] + bias);
        AT_ST(&a0[(rowbase + lk * 4 + r4) * 1024 + colH], f2bf(v));
      }
    }
    BAR();
    // ---- Phases B,C,D: h = tanh(h_prev) @ W_h[l3] + b_h[l3]; tanh on write ----
    for (int l3 = 0; l3 < 3; ++l3) {
      const unsigned short* src = (l3 & 1) ? a1 : a0;
      unsigned short* dst = (l3 & 1) ? a0 : a1;
      f32x4 acc = {0.f, 0.f, 0.f, 0.f};
      const unsigned short* arow = src + (rowbase + lr) * 1024 + lk * 8;
      const unsigned short* bbase = sWh[l3] + lk * 128 + lr * 8;
#pragma unroll 8
      for (int kk = 0; kk < 32; ++kk) {
        short8 a = ld_frag(arow + kk * 32);
        short8 b = *(const short8*)(bbase + kk * 512);
        acc = __builtin_amdgcn_mfma_f32_16x16x32_bf16(a, b, acc, 0, 0, 0);
      }
      float bias = sBh[l3][lr];
#pragma unroll
      for (int r4 = 0; r4 < 4; ++r4) {
        float v = tanhf(acc[r4] + bias);
        AT_ST(&dst[(rowbase + lk * 4 + r4) * 1024 + colH], f2bf(v));
      }
      BAR();
    }
    // ---- Phase E: f = a1 @ W_out + b_out ; y += dt*f ; emit out[:,t+1,:] ----
    float dt = sDt[t];
    if (j < 16) {
      f32x4 acc = {0.f, 0.f, 0.f, 0.f};
      const unsigned short* arow = a1 + (rowbase + lr) * 1024 + lk * 8;
      const unsigned short* bbase = sWout + lk * 128 + lr * 8;
#pragma unroll 8
      for (int kk = 0; kk < 32; ++kk) {
        short8 a = ld_frag(arow + kk * 32);
        short8 b = *(const short8*)(bbase + kk * 512);
        acc = __builtin_amdgcn_mfma_f32_16x16x32_bf16(a, b, acc, 0, 0, 0);
      }
      int col = j * 16 + lr;
#pragma unroll
      for (int r4 = 0; r4 < 4; ++r4) {
        float f = acc[r4] + sBout[lr];
        float yv = yreg[r4] + dt * f;
        yreg[r4] = yv;
        int row = rowbase + lk * 4 + r4;
        AT_ST(&ybf[row * 256 + col], f2bf(yv));  // coherent broadcast copy
        out[(row * 128 + t + 1) * 256 + col] = yv;  // host-read only, cached
      }
    }
    BAR();
  }
}

extern "C" void kernel_launch(void* const* d_in, const int* in_sizes, int n_in,
                              void* d_out, int out_size, void* d_ws, size_t ws_size,
                              hipStream_t stream) {
  (void)in_sizes; (void)n_in; (void)out_size; (void)ws_size;
  const float* x    = (const float*)d_in[0];
  const float* ts   = (const float*)d_in[1];
  const float* Win  = (const float*)d_in[2];
  const float* bin  = (const float*)d_in[3];
  const float* Wh   = (const float*)d_in[4];
  const float* bh   = (const float*)d_in[5];
  const float* Wout = (const float*)d_in[6];
  const float* bout = (const float*)d_in[7];
  float* out = (float*)d_out;

  char* ws = (char*)d_ws;
  unsigned* cnt = (unsigned*)ws;                                   // 4 KB counters
  unsigned short* ybf = (unsigned short*)(ws + 4096);              // 128 KB bf16 y
  unsigned short* a0 = (unsigned short*)(ws + 4096 + 131072);      // 512 KB
  unsigned short* a1 = (unsigned short*)(ws + 4096 + 131072 + 524288);  // 512 KB

  hipMemsetAsync(ws, 0, 4096, stream);  // zero barrier counters each call

  // Persistent spin-barrier kernel: co-residency of all 256 blocks is required.
  // Cooperative launch guarantees it; fall back to plain launch if rejected.
  void* args[] = {(void*)&x,    (void*)&ts,  (void*)&Win,  (void*)&bin,
                  (void*)&Wh,   (void*)&bh,  (void*)&Wout, (void*)&bout,
                  (void*)&out,  (void*)&cnt, (void*)&ybf,  (void*)&a0,
                  (void*)&a1};
  hipError_t e = hipLaunchCooperativeKernel((const void*)node_persistent,
                                            dim3(256), dim3(256), args, 0, stream);
  if (e != hipSuccess) {
    hipLaunchKernelGGL(node_persistent, dim3(256), dim3(256), 0, stream,
                       x, ts, Win, bin, Wh, bh, Wout, bout, out, cnt, ybf, a0, a1);
  }
}